// Round 4
// baseline (301.196 us; speedup 1.0000x reference)
//
#include <hip/hip_runtime.h>
#include <hip/hip_bf16.h>
#include <stdint.h>

#define IN_SZ   256
#define OUT_SZ  256
#define RANK    60
#define NSEL    256
#define BATCH   1024
#define WELEMS  (IN_SZ * OUT_SZ)   // 65536 elems per channel

typedef __attribute__((ext_vector_type(8))) short          short8;
typedef __attribute__((ext_vector_type(4))) float          f32x4;
typedef __attribute__((ext_vector_type(4))) unsigned short u16x4;

static __device__ __forceinline__ unsigned short f32_to_bf16(float f) {
    union { float f; uint32_t u; } c; c.f = f;
    uint32_t u = c.u;
    u += 0x7fffu + ((u >> 16) & 1u);   // RNE
    return (unsigned short)(u >> 16);
}

// -----------------------------------------------------------------------------
// Kernel 1: W_sel = U[idx] @ V -> bf16 in B-FRAGMENT-MAJOR layout:
//   wt[n][(i>>3)*2048 + o*8 + (i&7)]
// (unchanged from R3 — verified correct)
// -----------------------------------------------------------------------------
__global__ __launch_bounds__(256) void synth_w(
    const float* __restrict__ U, const float* __restrict__ V,
    const int* __restrict__ idx, unsigned short* __restrict__ wt)
{
    __shared__ unsigned short Cs[16][2064];

    int bid = blockIdx.x;                  // 512 blocks
    int L   = (bid & 7) * 64 + (bid >> 3);
    int ic  = L >> 4;
    int g16 = L & 15;

    int tid = threadIdx.x, lane = tid & 63, wv = tid >> 6;

    int arow = lane & 15;
    int c    = idx[g16 * 16 + arow];
    short8 afr[2];
    #pragma unroll
    for (int ks = 0; ks < 2; ++ks) {
        short8 h;
        #pragma unroll
        for (int j = 0; j < 8; ++j) {
            int r = ks * 32 + (lane >> 4) * 8 + j;
            float u = (r < RANK) ? U[c * RANK + r] : 0.f;
            h[j] = (short)f32_to_bf16(u);
        }
        afr[ks] = h;
    }

    const float* Vb = V + (size_t)ic * 2048;
    #pragma unroll 2
    for (int mt = 0; mt < 32; ++mt) {
        int mloc = (wv * 32 + mt) * 16 + (lane & 15);
        f32x4 acc = {};
        #pragma unroll
        for (int ks = 0; ks < 2; ++ks) {
            short8 b;
            #pragma unroll
            for (int j = 0; j < 8; ++j) {
                int r = ks * 32 + (lane >> 4) * 8 + j;
                float v = (r < RANK) ? Vb[(size_t)r * WELEMS + mloc] : 0.f;
                b[j] = (short)f32_to_bf16(v);
            }
            acc = __builtin_amdgcn_mfma_f32_16x16x32_bf16(afr[ks], b, acc, 0, 0, 0);
        }
        #pragma unroll
        for (int j = 0; j < 4; ++j) {
            int nl = (lane >> 4) * 4 + j;
            Cs[nl][wv * 512 + mt * 16 + (lane & 15)] = f32_to_bf16(acc[j]);
        }
    }
    __syncthreads();

    #pragma unroll
    for (int t0 = 0; t0 < 16; ++t0) {
        int t  = t0 * 256 + tid;
        int nl = t >> 8;
        int o  = t & 255;
        short8 h;
        #pragma unroll
        for (int il = 0; il < 8; ++il) h[il] = (short)Cs[nl][il * 256 + o];
        int n = g16 * 16 + nl;
        size_t base = (size_t)n * WELEMS + (size_t)ic * 2048 + (size_t)o * 8;
        *reinterpret_cast<short8*>(wt + base) = h;
    }
}

// -----------------------------------------------------------------------------
// Kernel 2: persistent quad-tile GEMM. 1024 blocks; block -> (n, quad); handles
// m-tiles quad*4..+4 of the same n. Cross-tile x-prefetch to regs (issued after
// the tile's last B-load so no B-wait drains it), 3-slot B pipeline, operand-
// swapped MFMA for a vectorized dwordx4 epilogue.
// -----------------------------------------------------------------------------
__global__ __launch_bounds__(256, 2) void gemm_k(
    const float* __restrict__ x, const int* __restrict__ idx,
    const unsigned short* __restrict__ wt, const float* __restrict__ bias,
    float* __restrict__ out)
{
    __shared__ __align__(16) unsigned short As[64 * 256];   // 32 KB

    int bid  = blockIdx.x;                 // 1024 blocks
    int L    = (bid & 7) * 128 + (bid >> 3);
    int n    = L >> 2;                     // 4 blocks per n -> same XCD
    int quad = L & 3;

    int tid = threadIdx.x, lane = tid & 63, wv = tid >> 6;
    int r16 = lane & 15, q = lane >> 4;
    int srow = tid >> 5, schunk = tid & 31;

    const unsigned short* wb = wt + (size_t)n * WELEMS;
    const float*          xb = x  + (size_t)n * (BATCH * IN_SZ);
    float*                ob = out + (size_t)n * (BATCH * OUT_SZ);

    int c = idx[n];
    f32x4 bv4[4];
    #pragma unroll
    for (int nf = 0; nf < 4; ++nf)
        bv4[nf] = *reinterpret_cast<const f32x4*>(
            &bias[(size_t)c * OUT_SZ + wv * 64 + nf * 16 + q * 4]);

    float4 va[8][2];                       // x-prefetch: 64 VGPR

    auto issue_x = [&](int mt) {
        const float* xn = xb + (size_t)mt * 64 * IN_SZ;
        #pragma unroll
        for (int p = 0; p < 8; ++p) {
            int row = p * 8 + srow;
            const float* gp = xn + (size_t)row * IN_SZ + schunk * 8;
            va[p][0] = *reinterpret_cast<const float4*>(gp);
            va[p][1] = *reinterpret_cast<const float4*>(gp + 4);
        }
    };
    auto write_lds = [&]() {
        #pragma unroll
        for (int p = 0; p < 8; ++p) {
            int row = p * 8 + srow;
            short8 h;
            h[0] = (short)f32_to_bf16(va[p][0].x); h[1] = (short)f32_to_bf16(va[p][0].y);
            h[2] = (short)f32_to_bf16(va[p][0].z); h[3] = (short)f32_to_bf16(va[p][0].w);
            h[4] = (short)f32_to_bf16(va[p][1].x); h[5] = (short)f32_to_bf16(va[p][1].y);
            h[6] = (short)f32_to_bf16(va[p][1].z); h[7] = (short)f32_to_bf16(va[p][1].w);
            int off = row * 512 + ((schunk * 16) ^ ((row & 7) << 4));   // bytes
            *reinterpret_cast<short8*>(&As[off >> 1]) = h;
        }
    };

    const unsigned short* wq = wb + q * 2048 + (size_t)(wv * 64 + r16) * 8;
    auto loadB = [&](int ks, short8* dst) {
        #pragma unroll
        for (int nf = 0; nf < 4; ++nf)
            dst[nf] = *reinterpret_cast<const short8*>(wq + ks * 8192 + nf * 128);
    };

    f32x4 acc[4][4] = {};
    short8 bf[3][4];

    // prologue
    loadB(0, bf[0]);
    loadB(1, bf[1]);
    issue_x(quad * 4);
    write_lds();           // implicit vmcnt wait on x (one-time cost)
    __syncthreads();

    for (int t = 0; t < 4; ++t) {
        int mt = quad * 4 + t;

        #pragma unroll
        for (int ks = 0; ks < 8; ++ks) {
            if (ks < 6) loadB(ks + 2, bf[(ks + 2) % 3]);
            if (ks == 5 && t < 3) issue_x(mt + 1);   // after last B-load of tile
            short8 af[4];
            #pragma unroll
            for (int mf = 0; mf < 4; ++mf) {
                int row = mf * 16 + r16;
                int off = row * 512 + ((ks * 64 + q * 16) ^ ((row & 7) << 4));
                af[mf] = *reinterpret_cast<const short8*>(&As[off >> 1]);
            }
            const short8* bb = bf[ks % 3];
            #pragma unroll
            for (int mf = 0; mf < 4; ++mf)
                #pragma unroll
                for (int nf = 0; nf < 4; ++nf)
                    acc[mf][nf] = __builtin_amdgcn_mfma_f32_16x16x32_bf16(
                        bb[nf], af[mf], acc[mf][nf], 0, 0, 0);   // SWAPPED operands
        }

        if (t < 3) {
            __syncthreads();       // everyone done reading As
            write_lds();           // waits x, rewrites As for tile t+1
            __syncthreads();
            loadB(0, bf[0]);       // re-arm B pipeline BEFORE stores:
            loadB(1, bf[1]);       // first B-waits of t+1 won't drain stores
        }

        // epilogue: transposed acc -> lane holds 4 consecutive o -> dwordx4
        float* on = ob + (size_t)mt * 64 * OUT_SZ;
        #pragma unroll
        for (int mf = 0; mf < 4; ++mf) {
            int row = mf * 16 + r16;
            #pragma unroll
            for (int nf = 0; nf < 4; ++nf) {
                f32x4 w = acc[mf][nf] + bv4[nf];
                *reinterpret_cast<f32x4*>(
                    &on[(size_t)row * OUT_SZ + wv * 64 + nf * 16 + q * 4]) = w;
                if (t < 3) acc[mf][nf] = (f32x4){0.f, 0.f, 0.f, 0.f};
            }
        }
    }
}

extern "C" void kernel_launch(void* const* d_in, const int* in_sizes, int n_in,
                              void* d_out, int out_size, void* d_ws, size_t ws_size,
                              hipStream_t stream) {
    const float* x    = (const float*)d_in[0];
    const int*   idx  = (const int*)  d_in[1];
    const float* U    = (const float*)d_in[2];
    const float* V    = (const float*)d_in[3];
    const float* bias = (const float*)d_in[4];
    float* out = (float*)d_out;
    unsigned short* wt = (unsigned short*)d_ws;   // 32 MB scratch
    (void)in_sizes; (void)n_in; (void)out_size; (void)ws_size;

    synth_w<<<dim3(512),  dim3(256), 0, stream>>>(U, V, idx, wt);
    gemm_k <<<dim3(1024), dim3(256), 0, stream>>>(x, idx, wt, bias, out);
}

// Round 5
// 281.245 us; speedup vs baseline: 1.0709x; 1.0709x over previous
//
#include <hip/hip_runtime.h>
#include <hip/hip_bf16.h>
#include <stdint.h>

#define IN_SZ   256
#define OUT_SZ  256
#define RANK    60
#define NSEL    256
#define BATCH   1024
#define WELEMS  (IN_SZ * OUT_SZ)   // 65536 elems per channel

typedef __attribute__((ext_vector_type(8))) short          short8;
typedef __attribute__((ext_vector_type(4))) float          f32x4;
typedef __attribute__((ext_vector_type(4))) unsigned short u16x4;

static __device__ __forceinline__ unsigned short f32_to_bf16(float f) {
    union { float f; uint32_t u; } c; c.f = f;
    uint32_t u = c.u;
    u += 0x7fffu + ((u >> 16) & 1u);   // RNE
    return (unsigned short)(u >> 16);
}

// -----------------------------------------------------------------------------
// Kernel 1: W_sel = U[idx] @ V -> bf16 in B-FRAGMENT-MAJOR layout:
//   wt[n][(i>>3)*2048 + o*8 + (i&7)]
// (unchanged — verified correct, ~24 µs)
// -----------------------------------------------------------------------------
__global__ __launch_bounds__(256) void synth_w(
    const float* __restrict__ U, const float* __restrict__ V,
    const int* __restrict__ idx, unsigned short* __restrict__ wt)
{
    __shared__ unsigned short Cs[16][2064];

    int bid = blockIdx.x;                  // 512 blocks
    int L   = (bid & 7) * 64 + (bid >> 3); // XCD swizzle: same-ic -> same XCD
    int ic  = L >> 4;
    int g16 = L & 15;

    int tid = threadIdx.x, lane = tid & 63, wv = tid >> 6;

    int arow = lane & 15;
    int c    = idx[g16 * 16 + arow];
    short8 afr[2];
    #pragma unroll
    for (int ks = 0; ks < 2; ++ks) {
        short8 h;
        #pragma unroll
        for (int j = 0; j < 8; ++j) {
            int r = ks * 32 + (lane >> 4) * 8 + j;
            float u = (r < RANK) ? U[c * RANK + r] : 0.f;
            h[j] = (short)f32_to_bf16(u);
        }
        afr[ks] = h;
    }

    const float* Vb = V + (size_t)ic * 2048;
    #pragma unroll 2
    for (int mt = 0; mt < 32; ++mt) {
        int mloc = (wv * 32 + mt) * 16 + (lane & 15);
        f32x4 acc = {};
        #pragma unroll
        for (int ks = 0; ks < 2; ++ks) {
            short8 b;
            #pragma unroll
            for (int j = 0; j < 8; ++j) {
                int r = ks * 32 + (lane >> 4) * 8 + j;
                float v = (r < RANK) ? Vb[(size_t)r * WELEMS + mloc] : 0.f;
                b[j] = (short)f32_to_bf16(v);
            }
            acc = __builtin_amdgcn_mfma_f32_16x16x32_bf16(afr[ks], b, acc, 0, 0, 0);
        }
        #pragma unroll
        for (int j = 0; j < 4; ++j) {
            int nl = (lane >> 4) * 4 + j;
            Cs[nl][wv * 512 + mt * 16 + (lane & 15)] = f32_to_bf16(acc[j]);
        }
    }
    __syncthreads();

    #pragma unroll
    for (int t0 = 0; t0 < 16; ++t0) {
        int t  = t0 * 256 + tid;
        int nl = t >> 8;
        int o  = t & 255;
        short8 h;
        #pragma unroll
        for (int il = 0; il < 8; ++il) h[il] = (short)Cs[nl][il * 256 + o];
        int n = g16 * 16 + nl;
        size_t base = (size_t)n * WELEMS + (size_t)ic * 2048 + (size_t)o * 8;
        *reinterpret_cast<short8*>(wt + base) = h;
    }
}

// -----------------------------------------------------------------------------
// Kernel 2: out[n] = x[n] @ W_sel[n] + bias[idx[n]]
// R3 structure (known-good 147 µs), single change: launch_bounds 3 -> 5
// blocks/CU. 32 KB LDS x 5 = 160 KB exactly; VGPR cap 102 >= 88 used.
// 20 phase-staggered waves/CU keep HBM busy through compute phases.
// -----------------------------------------------------------------------------
__global__ __launch_bounds__(256, 5) void gemm_k(
    const float* __restrict__ x, const int* __restrict__ idx,
    const unsigned short* __restrict__ wt, const float* __restrict__ bias,
    float* __restrict__ out)
{
    __shared__ __align__(16) unsigned short As[64 * 256];   // 32 KB

    int bid = blockIdx.x;                  // 4096 blocks
    int L   = (bid & 7) * 512 + (bid >> 3);
    int n   = L >> 4;                      // 16 m-tiles of same n -> same XCD
    int mt  = L & 15;

    int tid  = threadIdx.x;
    int lane = tid & 63;
    int wv   = tid >> 6;
    int r16  = lane & 15;
    int q    = lane >> 4;

    const float*          xn = x  + (size_t)n * (BATCH * IN_SZ) + (size_t)mt * 64 * IN_SZ;
    const unsigned short* wb = wt + (size_t)n * WELEMS;

    // ---- stage x-tile: 64 rows x 256 f32 -> bf16, rows of 512B, XOR swizzle ----
    #pragma unroll
    for (int p = 0; p < 8; ++p) {
        int id    = p * 256 + tid;         // 2048 items of 8 floats
        int row   = id >> 5;
        int chunk = id & 31;
        const float* gp = xn + (size_t)row * IN_SZ + chunk * 8;
        float4 v0 = *reinterpret_cast<const float4*>(gp);
        float4 v1 = *reinterpret_cast<const float4*>(gp + 4);
        short8 h;
        h[0] = (short)f32_to_bf16(v0.x); h[1] = (short)f32_to_bf16(v0.y);
        h[2] = (short)f32_to_bf16(v0.z); h[3] = (short)f32_to_bf16(v0.w);
        h[4] = (short)f32_to_bf16(v1.x); h[5] = (short)f32_to_bf16(v1.y);
        h[6] = (short)f32_to_bf16(v1.z); h[7] = (short)f32_to_bf16(v1.w);
        int off = row * 512 + ((chunk * 16) ^ ((row & 7) << 4));   // bytes
        *reinterpret_cast<short8*>(&As[off >> 1]) = h;
    }
    __syncthreads();   // the only barrier

    f32x4 acc[4][4] = {};

    #pragma unroll
    for (int ks = 0; ks < 8; ++ks) {
        short8 af[4], bf[4];
        #pragma unroll
        for (int mf = 0; mf < 4; ++mf) {
            int row = mf * 16 + r16;
            int off = row * 512 + ((ks * 64 + q * 16) ^ ((row & 7) << 4));
            af[mf] = *reinterpret_cast<const short8*>(&As[off >> 1]);
        }
        #pragma unroll
        for (int nf = 0; nf < 4; ++nf) {
            int o = wv * 64 + nf * 16 + r16;
            bf[nf] = *reinterpret_cast<const short8*>(
                wb + (size_t)((ks * 4 + q) * 2048 + o * 8));
        }
        #pragma unroll
        for (int mf = 0; mf < 4; ++mf)
            #pragma unroll
            for (int nf = 0; nf < 4; ++nf)
                acc[mf][nf] = __builtin_amdgcn_mfma_f32_16x16x32_bf16(
                    af[mf], bf[nf], acc[mf][nf], 0, 0, 0);
    }

    // ---- epilogue: + bias, store f32 ----
    int c = idx[n];
    float bv[4];
    #pragma unroll
    for (int nf = 0; nf < 4; ++nf)
        bv[nf] = bias[(size_t)c * OUT_SZ + wv * 64 + nf * 16 + r16];

    float* on = out + (size_t)n * (BATCH * OUT_SZ) + (size_t)mt * 64 * OUT_SZ;
    #pragma unroll
    for (int mf = 0; mf < 4; ++mf) {
        int r0 = mf * 16 + q * 4;
        #pragma unroll
        for (int nf = 0; nf < 4; ++nf) {
            int o = wv * 64 + nf * 16 + r16;
            #pragma unroll
            for (int j = 0; j < 4; ++j)
                on[(size_t)(r0 + j) * OUT_SZ + o] = acc[mf][nf][j] + bv[nf];
        }
    }
}

extern "C" void kernel_launch(void* const* d_in, const int* in_sizes, int n_in,
                              void* d_out, int out_size, void* d_ws, size_t ws_size,
                              hipStream_t stream) {
    const float* x    = (const float*)d_in[0];
    const int*   idx  = (const int*)  d_in[1];
    const float* U    = (const float*)d_in[2];
    const float* V    = (const float*)d_in[3];
    const float* bias = (const float*)d_in[4];
    float* out = (float*)d_out;
    unsigned short* wt = (unsigned short*)d_ws;   // 32 MB scratch
    (void)in_sizes; (void)n_in; (void)out_size; (void)ws_size;

    synth_w<<<dim3(512),  dim3(256), 0, stream>>>(U, V, idx, wt);
    gemm_k <<<dim3(4096), dim3(256), 0, stream>>>(x, idx, wt, bias, out);
}

// Round 6
// 182.356 us; speedup vs baseline: 1.6517x; 1.5423x over previous
//
#include <hip/hip_runtime.h>
#include <hip/hip_bf16.h>
#include <stdint.h>

#define IN_SZ   256
#define OUT_SZ  256
#define RANK    60
#define NSEL    256
#define BATCH   1024
#define WELEMS  (IN_SZ * OUT_SZ)   // 65536 elems per channel

typedef __attribute__((ext_vector_type(8))) short          short8;
typedef __attribute__((ext_vector_type(4))) float          f32x4;
typedef __attribute__((ext_vector_type(4))) unsigned short u16x4;

static __device__ __forceinline__ unsigned short f32_to_bf16(float f) {
    union { float f; uint32_t u; } c; c.f = f;
    uint32_t u = c.u;
    u += 0x7fffu + ((u >> 16) & 1u);   // RNE
    return (unsigned short)(u >> 16);
}

// -----------------------------------------------------------------------------
// Kernel 1: W_sel = U[idx] @ V -> bf16 in B-FRAGMENT-MAJOR layout:
//   wt[n][(i>>3)*2048 + o*8 + (i&7)]
// (unchanged — verified correct, ~24 µs)
// -----------------------------------------------------------------------------
__global__ __launch_bounds__(256) void synth_w(
    const float* __restrict__ U, const float* __restrict__ V,
    const int* __restrict__ idx, unsigned short* __restrict__ wt)
{
    __shared__ unsigned short Cs[16][2064];

    int bid = blockIdx.x;                  // 512 blocks
    int L   = (bid & 7) * 64 + (bid >> 3); // XCD swizzle: same-ic -> same XCD
    int ic  = L >> 4;
    int g16 = L & 15;

    int tid = threadIdx.x, lane = tid & 63, wv = tid >> 6;

    int arow = lane & 15;
    int c    = idx[g16 * 16 + arow];
    short8 afr[2];
    #pragma unroll
    for (int ks = 0; ks < 2; ++ks) {
        short8 h;
        #pragma unroll
        for (int j = 0; j < 8; ++j) {
            int r = ks * 32 + (lane >> 4) * 8 + j;
            float u = (r < RANK) ? U[c * RANK + r] : 0.f;
            h[j] = (short)f32_to_bf16(u);
        }
        afr[ks] = h;
    }

    const float* Vb = V + (size_t)ic * 2048;
    #pragma unroll 2
    for (int mt = 0; mt < 32; ++mt) {
        int mloc = (wv * 32 + mt) * 16 + (lane & 15);
        f32x4 acc = {};
        #pragma unroll
        for (int ks = 0; ks < 2; ++ks) {
            short8 b;
            #pragma unroll
            for (int j = 0; j < 8; ++j) {
                int r = ks * 32 + (lane >> 4) * 8 + j;
                float v = (r < RANK) ? Vb[(size_t)r * WELEMS + mloc] : 0.f;
                b[j] = (short)f32_to_bf16(v);
            }
            acc = __builtin_amdgcn_mfma_f32_16x16x32_bf16(afr[ks], b, acc, 0, 0, 0);
        }
        #pragma unroll
        for (int j = 0; j < 4; ++j) {
            int nl = (lane >> 4) * 4 + j;
            Cs[nl][wv * 512 + mt * 16 + (lane & 15)] = f32_to_bf16(acc[j]);
        }
    }
    __syncthreads();

    #pragma unroll
    for (int t0 = 0; t0 < 16; ++t0) {
        int t  = t0 * 256 + tid;
        int nl = t >> 8;
        int o  = t & 255;
        short8 h;
        #pragma unroll
        for (int il = 0; il < 8; ++il) h[il] = (short)Cs[nl][il * 256 + o];
        int n = g16 * 16 + nl;
        size_t base = (size_t)n * WELEMS + (size_t)ic * 2048 + (size_t)o * 8;
        *reinterpret_cast<short8*>(wt + base) = h;
    }
}

// -----------------------------------------------------------------------------
// Kernel 2: out[n] = x[n] @ W_sel[n] + bias[idx[n]]
// BM=32, BN=256, full K. x-tile DMA'd f32 via global_load_lds (no VGPR dest ->
// unlimited outstanding HBM reads), XOR swizzle applied to the per-lane GLOBAL
// source (LDS dest stays linear, m173 pattern) and to the ds_read side.
// bf16 convert at fragment build (RNE, identical numerics). Operand-swapped
// MFMA -> lane holds 4 consecutive o -> dwordx4 epilogue stores.
// LDS 32 KB -> 5 blocks/CU; VGPR ~60 under a 128 cap.
// -----------------------------------------------------------------------------
__global__ __launch_bounds__(256, 4) void gemm_k(
    const float* __restrict__ x, const int* __restrict__ idx,
    const unsigned short* __restrict__ wt, const float* __restrict__ bias,
    float* __restrict__ out)
{
    __shared__ __align__(16) float As[32 * 256];   // 32 KB f32

    int bid = blockIdx.x;                  // 8192 blocks
    int L   = (bid & 7) * 1024 + (bid >> 3);
    int n   = L >> 5;                      // 32 m-tiles of same n -> same XCD
    int mt  = L & 31;

    int tid  = threadIdx.x;
    int lane = tid & 63;
    int wv   = tid >> 6;
    int r16  = lane & 15;
    int q    = lane >> 4;

    const float*          xn = x  + (size_t)n * (BATCH * IN_SZ) + (size_t)mt * 32 * IN_SZ;
    const unsigned short* wb = wt + (size_t)n * WELEMS;

    // ---- DMA stage: 32 rows x 1 KB; lane l sources chunk (l ^ (row&7)) ----
    // LDS[row][c] = x[row][c ^ (row&7)]  (16B chunks), dest linear per m104.
    #pragma unroll
    for (int j = 0; j < 8; ++j) {
        int row = wv * 8 + j;
        const float* gp = xn + (size_t)row * IN_SZ + ((lane ^ (row & 7)) << 2);
        __builtin_amdgcn_global_load_lds(
            (const __attribute__((address_space(1))) void*)gp,
            (__attribute__((address_space(3))) void*)(&As[row * 256]),
            16, 0, 0);
    }
    __syncthreads();   // drains DMA; the only barrier

    f32x4 acc[2][4] = {};
    const unsigned short* wq = wb + q * 2048 + (size_t)(wv * 64 + r16) * 8;

    #pragma unroll
    for (int ks = 0; ks < 8; ++ks) {
        short8 af[2], bf[4];
        #pragma unroll
        for (int mf = 0; mf < 2; ++mf) {
            int row = mf * 16 + r16;
            int c0  = ks * 8 + q * 2;          // 16B-chunk index, pre-swizzle
            int s   = row & 7;
            f32x4 lo = *reinterpret_cast<const f32x4*>(&As[row * 256 + (((c0    ) ^ s) << 2)]);
            f32x4 hi = *reinterpret_cast<const f32x4*>(&As[row * 256 + (((c0 + 1) ^ s) << 2)]);
            short8 h;
            h[0] = (short)f32_to_bf16(lo[0]); h[1] = (short)f32_to_bf16(lo[1]);
            h[2] = (short)f32_to_bf16(lo[2]); h[3] = (short)f32_to_bf16(lo[3]);
            h[4] = (short)f32_to_bf16(hi[0]); h[5] = (short)f32_to_bf16(hi[1]);
            h[6] = (short)f32_to_bf16(hi[2]); h[7] = (short)f32_to_bf16(hi[3]);
            af[mf] = h;
        }
        #pragma unroll
        for (int nf = 0; nf < 4; ++nf)
            bf[nf] = *reinterpret_cast<const short8*>(wq + ks * 8192 + nf * 128);
        #pragma unroll
        for (int mf = 0; mf < 2; ++mf)
            #pragma unroll
            for (int nf = 0; nf < 4; ++nf)
                acc[mf][nf] = __builtin_amdgcn_mfma_f32_16x16x32_bf16(
                    bf[nf], af[mf], acc[mf][nf], 0, 0, 0);   // swapped: D = out^T frag
    }

    // ---- epilogue: + bias, dwordx4 stores (lane holds 4 consecutive o) ----
    int c = idx[n];
    float* on = out + (size_t)n * (BATCH * OUT_SZ) + (size_t)mt * 32 * OUT_SZ;
    #pragma unroll
    for (int nf = 0; nf < 4; ++nf) {
        f32x4 bv = *reinterpret_cast<const f32x4*>(
            &bias[(size_t)c * OUT_SZ + wv * 64 + nf * 16 + q * 4]);
        #pragma unroll
        for (int mf = 0; mf < 2; ++mf) {
            f32x4 w = acc[mf][nf] + bv;
            *reinterpret_cast<f32x4*>(
                &on[(size_t)(mf * 16 + r16) * OUT_SZ + wv * 64 + nf * 16 + q * 4]) = w;
        }
    }
}

extern "C" void kernel_launch(void* const* d_in, const int* in_sizes, int n_in,
                              void* d_out, int out_size, void* d_ws, size_t ws_size,
                              hipStream_t stream) {
    const float* x    = (const float*)d_in[0];
    const int*   idx  = (const int*)  d_in[1];
    const float* U    = (const float*)d_in[2];
    const float* V    = (const float*)d_in[3];
    const float* bias = (const float*)d_in[4];
    float* out = (float*)d_out;
    unsigned short* wt = (unsigned short*)d_ws;   // 32 MB scratch
    (void)in_sizes; (void)n_in; (void)out_size; (void)ws_size;

    synth_w<<<dim3(512),  dim3(256), 0, stream>>>(U, V, idx, wt);
    gemm_k <<<dim3(8192), dim3(256), 0, stream>>>(x, idx, wt, bias, out);
}